// Round 1
// baseline (1643.067 us; speedup 1.0000x reference)
//
#include <hip/hip_runtime.h>
#include <float.h>

#define B_ 8
#define T_ 2048
#define E_ 1024
#define DG 256   // folded/group width: 4 groups * 64

// ---------------- fold Wq columns: Wqf[d,c] = sum_r Wq[d, c + 256 r] ----------------
__global__ __launch_bounds__(256) void fold_wq(const float* __restrict__ Wq,
                                               const float* __restrict__ bq,
                                               float* __restrict__ Wqf,
                                               float* __restrict__ bqf) {
  int idx = blockIdx.x * 256 + threadIdx.x;      // 0 .. 1024*256
  int d = idx >> 8, c = idx & 255;
  const float* row = Wq + (size_t)d * 1024;
  Wqf[idx] = row[c] + row[c + 256] + row[c + 512] + row[c + 768];
  if (idx < 256) bqf[idx] = bq[idx] + bq[idx + 256] + bq[idx + 512] + bq[idx + 768];
}

// ---------------- projection GEMM: C = x @ W + b  (M=16384, N=768 split 3x256, K=1024)
// tile 128x64, 256 threads, 8x4 micro-tile per thread, fp32
__global__ __launch_bounds__(256) void proj_gemm(
    const float* __restrict__ x,
    const float* __restrict__ Wqf, const float* __restrict__ bqf,
    const float* __restrict__ Wk,  const float* __restrict__ bk,
    const float* __restrict__ Wv,  const float* __restrict__ bv,
    float* __restrict__ Pq, float* __restrict__ Kg, float* __restrict__ Vg) {
  __shared__ float As[16][132];   // [k][m], pad keeps staging writes ~2-way
  __shared__ float Bs[16][68];    // [k][n]
  int bm = blockIdx.x;            // 0..127
  int n0 = blockIdx.y * 64;       // 0..704
  const float* W; const float* bias; float* C; int nc;
  if (n0 < 256)      { W = Wqf; bias = bqf; C = Pq; nc = n0; }
  else if (n0 < 512) { W = Wk;  bias = bk;  C = Kg; nc = n0 - 256; }
  else               { W = Wv;  bias = bv;  C = Vg; nc = n0 - 512; }
  int tid = threadIdx.x;
  int tx = tid & 15, ty = tid >> 4;
  int m0 = bm * 128;
  int arow = tid >> 2;            // 0..63
  int ak   = (tid & 3) * 4;       // 0,4,8,12
  int brow = tid >> 4;            // 0..15 (k)
  int bcol = (tid & 15) * 4;      // 0..60
  float acc[8][4] = {};
  for (int k0 = 0; k0 < 1024; k0 += 16) {
#pragma unroll
    for (int q = 0; q < 2; ++q) {
      int r = q * 64 + arow;
      float4 v = *(const float4*)(x + (size_t)(m0 + r) * 1024 + k0 + ak);
      As[ak + 0][r] = v.x; As[ak + 1][r] = v.y; As[ak + 2][r] = v.z; As[ak + 3][r] = v.w;
    }
    {
      float4 v = *(const float4*)(W + (size_t)(k0 + brow) * 256 + nc + bcol);
      *(float4*)&Bs[brow][bcol] = v;
    }
    __syncthreads();
#pragma unroll
    for (int kk = 0; kk < 16; ++kk) {
      float a[8], b[4];
      *(float4*)&a[0] = *(const float4*)&As[kk][ty * 8];
      *(float4*)&a[4] = *(const float4*)&As[kk][ty * 8 + 4];
      *(float4*)&b[0] = *(const float4*)&Bs[kk][tx * 4];
#pragma unroll
      for (int i = 0; i < 8; ++i)
#pragma unroll
        for (int j = 0; j < 4; ++j)
          acc[i][j] += a[i] * b[j];
    }
    __syncthreads();
  }
#pragma unroll
  for (int i = 0; i < 8; ++i) {
    float4 v;
    v.x = acc[i][0] + bias[nc + tx * 4 + 0];
    v.y = acc[i][1] + bias[nc + tx * 4 + 1];
    v.z = acc[i][2] + bias[nc + tx * 4 + 2];
    v.w = acc[i][3] + bias[nc + tx * 4 + 3];
    *(float4*)(C + (size_t)(m0 + ty * 8 + i) * 256 + nc + tx * 4) = v;
  }
}

// ---------------- fused causal attention over the folded 256-dim ----------------
// One WG per (batch, 32-row Q tile). 256 threads: row = tid>>3 (32 rows), cg = tid&7.
// Thread owns 4 score cols (cg*4..+3) and 32 O cols (cg*4 + q*32 + e).
__global__ __launch_bounds__(256) void attn_kernel(
    const float* __restrict__ Pq, const float* __restrict__ Kg,
    const float* __restrict__ Vg, float* __restrict__ out) {
  __shared__ float Qs[32][260];   // pad 260: float4 reads aligned + conflict-free
  __shared__ float Ks[32][257];   // pad 257: scalar k-reads conflict-free across rows
  __shared__ float Vs[32][260];   // pad 260: float4 col-reads conflict-free
  __shared__ float Ps[32][33];
  int bid = blockIdx.x;
  int b  = bid >> 6;
  int wg = bid & 63;
  int tile = (wg & 1) ? (63 - (wg >> 1)) : (wg >> 1);   // pair long+short tiles
  int r0 = tile * 32;
  int tid = threadIdx.x;
  int row = tid >> 3;       // 0..31
  int cg  = tid & 7;        // 0..7
  int t = r0 + row;
  const float* Qb = Pq + ((size_t)b * T_ + r0) * DG;
  const float* Kb = Kg + (size_t)b * T_ * DG;
  const float* Vb = Vg + (size_t)b * T_ * DG;
  // load Q tile (32x256)
#pragma unroll
  for (int q = 0; q < 8; ++q) {
    int f = q * 1024 + tid * 4;
    int r = f >> 8, c = f & 255;
    *(float4*)&Qs[r][c] = *(const float4*)(Qb + (size_t)r * DG + c);
  }
  float o[32] = {};
  float m_old = -FLT_MAX, l = 0.f;
  int c0 = cg * 4;
  int nblk = tile + 1;
  for (int sb = 0; sb < nblk; ++sb) {
    int s0 = sb * 32;
    __syncthreads();   // protect K/V/P from previous iteration readers (also covers Q load)
#pragma unroll
    for (int q = 0; q < 8; ++q) {
      int f = q * 1024 + tid * 4;
      int r = f >> 8, c = f & 255;
      float4 kv = *(const float4*)(Kb + (size_t)(s0 + r) * DG + c);
      Ks[r][c + 0] = kv.x; Ks[r][c + 1] = kv.y; Ks[r][c + 2] = kv.z; Ks[r][c + 3] = kv.w;
      *(float4*)&Vs[r][c] = *(const float4*)(Vb + (size_t)(s0 + r) * DG + c);
    }
    __syncthreads();
    // scores: 4 dots of length 256
    float sc[4] = {0.f, 0.f, 0.f, 0.f};
#pragma unroll 4
    for (int k = 0; k < 256; k += 4) {
      float4 qv = *(const float4*)&Qs[row][k];
#pragma unroll
      for (int j = 0; j < 4; ++j) {
        sc[j] += qv.x * Ks[c0 + j][k]     + qv.y * Ks[c0 + j][k + 1]
               + qv.z * Ks[c0 + j][k + 2] + qv.w * Ks[c0 + j][k + 3];
      }
    }
    // causal mask
#pragma unroll
    for (int j = 0; j < 4; ++j)
      if (s0 + c0 + j > t) sc[j] = -FLT_MAX;
    float bmax = fmaxf(fmaxf(sc[0], sc[1]), fmaxf(sc[2], sc[3]));
#pragma unroll
    for (int off = 1; off < 8; off <<= 1)
      bmax = fmaxf(bmax, __shfl_xor(bmax, off, 64));
    float m_new = fmaxf(m_old, bmax);
    float p[4], psum = 0.f;
#pragma unroll
    for (int j = 0; j < 4; ++j) { p[j] = expf(sc[j] - m_new); psum += p[j]; }
#pragma unroll
    for (int off = 1; off < 8; off <<= 1)
      psum += __shfl_xor(psum, off, 64);
    Ps[row][c0 + 0] = p[0]; Ps[row][c0 + 1] = p[1];
    Ps[row][c0 + 2] = p[2]; Ps[row][c0 + 3] = p[3];
    __syncthreads();
    float scale = expf(m_old - m_new);
    l = l * scale + psum;
#pragma unroll
    for (int i = 0; i < 32; ++i) o[i] *= scale;
    // PV: O[row, cg*4 + q*32 + e] += P[row, s] * V[s, ...]
    for (int s = 0; s < 32; ++s) {
      float pv = Ps[row][s];
#pragma unroll
      for (int q = 0; q < 8; ++q) {
        float4 v = *(const float4*)&Vs[s][c0 + q * 32];
        o[q * 4 + 0] += pv * v.x; o[q * 4 + 1] += pv * v.y;
        o[q * 4 + 2] += pv * v.z; o[q * 4 + 3] += pv * v.w;
      }
    }
    m_old = m_new;
  }
  // epilogue: normalize by l, post-softmax /sqrt(64)=8, write 4 tiled copies
  float inv = 1.0f / (l * 8.0f);
  float* orow = out + ((size_t)b * T_ + t) * 1024;
#pragma unroll
  for (int q = 0; q < 8; ++q) {
    float4 v;
    v.x = o[q * 4 + 0] * inv; v.y = o[q * 4 + 1] * inv;
    v.z = o[q * 4 + 2] * inv; v.w = o[q * 4 + 3] * inv;
    int c = c0 + q * 32;
    *(float4*)(orow + c)       = v;
    *(float4*)(orow + 256 + c) = v;
    *(float4*)(orow + 512 + c) = v;
    *(float4*)(orow + 768 + c) = v;
  }
}

extern "C" void kernel_launch(void* const* d_in, const int* in_sizes, int n_in,
                              void* d_out, int out_size, void* d_ws, size_t ws_size,
                              hipStream_t stream) {
  const float* x  = (const float*)d_in[0];
  const float* Wq = (const float*)d_in[1];
  const float* bq = (const float*)d_in[2];
  const float* Wk = (const float*)d_in[3];
  const float* bk = (const float*)d_in[4];
  const float* Wv = (const float*)d_in[5];
  const float* bv = (const float*)d_in[6];
  float* out = (float*)d_out;
  char* ws = (char*)d_ws;
  float* Wqf = (float*)ws;                          // 1 MB
  float* bqf = (float*)(ws + (1 << 20));            // 1 KB (padded to 4 KB)
  float* Pq  = (float*)(ws + (1 << 20) + 4096);     // 16 MB
  float* Kg  = Pq + (size_t)16384 * 256;            // 16 MB
  float* Vg  = Kg + (size_t)16384 * 256;            // 16 MB  (total ~51.3 MB)

  fold_wq<<<1024, 256, 0, stream>>>(Wq, bq, Wqf, bqf);
  proj_gemm<<<dim3(128, 12), 256, 0, stream>>>(x, Wqf, bqf, Wk, bk, Wv, bv, Pq, Kg, Vg);
  attn_kernel<<<512, 256, 0, stream>>>(Pq, Kg, Vg, out);
}

// Round 4
// 474.234 us; speedup vs baseline: 3.4647x; 3.4647x over previous
//
#include <hip/hip_runtime.h>
#include <float.h>
#include <stdint.h>

#define T_ 2048
#define DG 256   // folded/group width: 4 groups * 64

typedef _Float16 half8 __attribute__((ext_vector_type(8)));
typedef _Float16 half4v __attribute__((ext_vector_type(4)));
typedef __fp16 fp16x2 __attribute__((ext_vector_type(2)));
typedef float f32x16 __attribute__((ext_vector_type(16)));

__device__ __forceinline__ void gload16(const void* g, void* l) {
  __builtin_amdgcn_global_load_lds(
      (const __attribute__((address_space(1))) unsigned int*)g,
      (__attribute__((address_space(3))) unsigned int*)l, 16, 0, 0);
}
// Explicit waits: 1-wave WG means __syncthreads may be elided (incl. its vmcnt
// drain) -- global_load_lds->ds_read has NO register dep, must fence manually.
#define WAIT_VM0()   do { asm volatile("s_waitcnt vmcnt(0)" ::: "memory"); __builtin_amdgcn_sched_barrier(0); } while (0)
#define WAIT_LGKM0() do { asm volatile("s_waitcnt lgkmcnt(0)" ::: "memory"); __builtin_amdgcn_sched_barrier(0); } while (0)

// ---------------- fold Wq columns: Wqf[d,c] = sum_r Wq[d, c + 256 r] ----------------
__global__ __launch_bounds__(256) void fold_wq(const float* __restrict__ Wq,
                                               const float* __restrict__ bq,
                                               float* __restrict__ Wqf,
                                               float* __restrict__ bqf) {
  int idx = blockIdx.x * 256 + threadIdx.x;      // 0 .. 1024*256
  int d = idx >> 8, c = idx & 255;
  const float* row = Wq + (size_t)d * 1024;
  Wqf[idx] = row[c] + row[c + 256] + row[c + 512] + row[c + 768];
  if (idx < 256) bqf[idx] = bq[idx] + bq[idx + 256] + bq[idx + 512] + bq[idx + 768];
}

// ---------------- projection GEMM: C = x @ W + b  (M=16384, N=768 split 3x256, K=1024)
// fp32 compute; epilogue emits fp16 Q (x log2e), fp16 K, fp16 V TRANSPOSED per batch
__global__ __launch_bounds__(256) void proj_gemm(
    const float* __restrict__ x,
    const float* __restrict__ Wqf, const float* __restrict__ bqf,
    const float* __restrict__ Wk,  const float* __restrict__ bk,
    const float* __restrict__ Wv,  const float* __restrict__ bv,
    _Float16* __restrict__ Qh, _Float16* __restrict__ Kh, _Float16* __restrict__ Vt) {
  __shared__ float As[16][132];
  __shared__ float Bs[16][68];
  int bm = blockIdx.x;            // 0..127
  int n0 = blockIdx.y * 64;       // 0..704
  const float* W; const float* bias; int nc;
  if (n0 < 256)      { W = Wqf; bias = bqf; nc = n0; }
  else if (n0 < 512) { W = Wk;  bias = bk;  nc = n0 - 256; }
  else               { W = Wv;  bias = bv;  nc = n0 - 512; }
  int tid = threadIdx.x;
  int tx = tid & 15, ty = tid >> 4;
  int m0 = bm * 128;
  int arow = tid >> 2;
  int ak   = (tid & 3) * 4;
  int brow = tid >> 4;
  int bcol = (tid & 15) * 4;
  float acc[8][4] = {};
  for (int k0 = 0; k0 < 1024; k0 += 16) {
#pragma unroll
    for (int q = 0; q < 2; ++q) {
      int r = q * 64 + arow;
      float4 v = *(const float4*)(x + (size_t)(m0 + r) * 1024 + k0 + ak);
      As[ak + 0][r] = v.x; As[ak + 1][r] = v.y; As[ak + 2][r] = v.z; As[ak + 3][r] = v.w;
    }
    {
      float4 v = *(const float4*)(W + (size_t)(k0 + brow) * 256 + nc + bcol);
      *(float4*)&Bs[brow][bcol] = v;
    }
    __syncthreads();
#pragma unroll
    for (int kk = 0; kk < 16; ++kk) {
      float a[8], b[4];
      *(float4*)&a[0] = *(const float4*)&As[kk][ty * 8];
      *(float4*)&a[4] = *(const float4*)&As[kk][ty * 8 + 4];
      *(float4*)&b[0] = *(const float4*)&Bs[kk][tx * 4];
#pragma unroll
      for (int i = 0; i < 8; ++i)
#pragma unroll
        for (int j = 0; j < 4; ++j)
          acc[i][j] += a[i] * b[j];
    }
    __syncthreads();
  }
  int row0 = m0 + ty * 8;
  if (n0 < 256) {          // Q: fold log2(e) so softmax can use exp2
#pragma unroll
    for (int i = 0; i < 8; ++i) {
      half4v h;
#pragma unroll
      for (int j = 0; j < 4; ++j)
        h[j] = (_Float16)((acc[i][j] + bias[nc + tx * 4 + j]) * 1.44269504f);
      *(half4v*)(Qh + (size_t)(row0 + i) * DG + nc + tx * 4) = h;
    }
  } else if (n0 < 512) {   // K
#pragma unroll
    for (int i = 0; i < 8; ++i) {
      half4v h;
#pragma unroll
      for (int j = 0; j < 4; ++j)
        h[j] = (_Float16)(acc[i][j] + bias[nc + tx * 4 + j]);
      *(half4v*)(Kh + (size_t)(row0 + i) * DG + nc + tx * 4) = h;
    }
  } else {                 // V transposed per batch: Vt[b][d][t]
#pragma unroll
    for (int j = 0; j < 4; ++j) {
      half8 hv;
#pragma unroll
      for (int i = 0; i < 8; ++i)
        hv[i] = (_Float16)(acc[i][j] + bias[nc + tx * 4 + j]);
      int bb = row0 >> 11, t0 = row0 & 2047;
      *(half8*)(Vt + ((size_t)(bb * DG + nc + tx * 4 + j)) * T_ + t0) = hv;
    }
  }
}

// ---------------- fused causal attention, swapped-operand MFMA, fp16 ----------------
// 1 wave per WG, 32 q-rows per WG. Double-buffered K/V LDS; staging of tile t+1
// issued BEFORE compute of tile t; explicit vmcnt fences (no __syncthreads).
__global__ __launch_bounds__(64, 1) void attn_mfma(
    const _Float16* __restrict__ Qg, const _Float16* __restrict__ Kg,
    const _Float16* __restrict__ Vtg, float* __restrict__ out) {
  __shared__ __align__(16) uint8_t smem[73728];   // 2 x (16KB K + 20KB V)
  const int l  = threadIdx.x;
  const int g  = l >> 5;          // lane group 0/1
  const int ln = l & 31;          // q column (B/C) and s/d row (A)
  const int bid = blockIdx.x;
  const int b   = bid & 7;                 // batch -> XCD pinning
  const int tile = 63 - (bid >> 3);        // longest tiles dispatched first
  const int q0 = tile * 32;

  // Q B-fragments: lane l holds Q[q0+ln][kk*16 + 8g + j], j=0..7
  const _Float16* Qrow = Qg + ((size_t)(b * T_ + q0 + ln)) * DG + 8 * g;
  half8 qf[16];
#pragma unroll
  for (int kk = 0; kk < 16; ++kk) qf[kk] = *(const half8*)(Qrow + kk * 16);

  f32x16 o[8] = {};               // O^T accumulator: 8 d-tiles x 16 regs
  float m_r = -1e30f, l_r = 0.0f;

  auto stage = [&](int s0, int buf) {
    uint8_t* Kl = smem + buf * 36864;
    uint8_t* Vl = Kl + 16384;
    // K tile: [32 s][32 slots of 16B], XOR-preswizzled source
#pragma unroll
    for (int i = 0; i < 16; ++i) {
      int slot = i * 64 + l;
      int row = slot >> 5, part = slot & 31;
      const _Float16* src = Kg + ((size_t)(b * T_ + s0 + row)) * DG + ((part ^ (row & 7)) << 3);
      gload16(src, Kl + i * 1024);
    }
    // V tile: [256 d][5 slots of 16B] (4 data + 1 pad)
#pragma unroll
    for (int i = 0; i < 20; ++i) {
      int slot = i * 64 + l;
      int d = slot / 5, part = slot - d * 5;
      int sp = (part < 4) ? (part << 3) : 0;   // pad slot loads garbage, never read
      const _Float16* src = Vtg + ((size_t)(b * DG + d)) * T_ + s0 + sp;
      gload16(src, Vl + i * 1024);
    }
  };

  stage(0, 0);
  int cur = 0;

  for (int kt = 0; kt <= tile; ++kt) {
    WAIT_VM0();                 // buffer `cur` staged and visible
    if (kt < tile) stage((kt + 1) * 32, cur ^ 1);   // overlap with compute below
    uint8_t* Klds = smem + cur * 36864;
    uint8_t* Vlds = Klds + 16384;

    // ---- scores S^T = K . Q^T ----
    f32x16 sa = {}, sb = {};
    const int xr = (ln & 7) << 4;
#pragma unroll
    for (int kk = 0; kk < 16; kk += 2) {
      half8 ka = *(const half8*)(Klds + ln * 512 + ((kk * 32 + 16 * g) ^ xr));
      half8 kb = *(const half8*)(Klds + ln * 512 + (((kk + 1) * 32 + 16 * g) ^ xr));
      sa = __builtin_amdgcn_mfma_f32_32x32x16_f16(ka, qf[kk],     sa, 0, 0, 0);
      sb = __builtin_amdgcn_mfma_f32_32x32x16_f16(kb, qf[kk + 1], sb, 0, 0, 0);
    }
    float s[16];
#pragma unroll
    for (int r = 0; r < 16; ++r) s[r] = sa[r] + sb[r];
    if (kt == tile) {   // causal mask, diagonal tile only
#pragma unroll
      for (int r = 0; r < 16; ++r) {
        int srow = (r & 3) + 8 * (r >> 2) + 4 * g;
        if (srow > ln) s[r] = -1e30f;
      }
    }
    // ---- online softmax (scores in log2 units) ----
    float pmax = s[0];
#pragma unroll
    for (int r = 1; r < 16; ++r) pmax = fmaxf(pmax, s[r]);
    pmax = fmaxf(pmax, __shfl_xor(pmax, 32));
    if (!__all(pmax <= m_r + 8.0f)) {     // defer-max rescale (T13)
      float mnew = fmaxf(m_r, pmax);
      float sc = exp2f(m_r - mnew);
      l_r *= sc;
#pragma unroll
      for (int dt = 0; dt < 8; ++dt)
#pragma unroll
        for (int r = 0; r < 16; ++r) o[dt][r] *= sc;
      m_r = mnew;
    }
    float p[16]; float psum = 0.0f;
#pragma unroll
    for (int r = 0; r < 16; ++r) { p[r] = exp2f(s[r] - m_r); psum += p[r]; }
    l_r += psum + __shfl_xor(psum, 32);

    // ---- P -> fp16 B-fragments, in-register (halves exchanged via shfl_xor 32) ----
    unsigned ph[8], xh[8];
#pragma unroll
    for (int i = 0; i < 8; ++i) {
      fp16x2 t2 = __builtin_amdgcn_cvt_pkrtz(p[2 * i], p[2 * i + 1]);
      ph[i] = __builtin_bit_cast(unsigned, t2);
      xh[i] = (unsigned)__shfl_xor((int)ph[i], 32);
    }
    union U { unsigned u[4]; half8 h; };
    U f0, f1;
    f0.u[0] = g ? xh[2] : ph[0]; f0.u[1] = g ? xh[3] : ph[1];
    f0.u[2] = g ? ph[2] : xh[0]; f0.u[3] = g ? ph[3] : xh[1];
    f1.u[0] = g ? xh[6] : ph[4]; f1.u[1] = g ? xh[7] : ph[5];
    f1.u[2] = g ? ph[6] : xh[4]; f1.u[3] = g ? ph[7] : xh[5];

    // ---- PV: O^T += Vt . P ----
#pragma unroll
    for (int dt = 0; dt < 8; ++dt) {
      half8 va = *(const half8*)(Vlds + (dt * 32 + ln) * 80 + 16 * g);
      o[dt] = __builtin_amdgcn_mfma_f32_32x32x16_f16(va, f0.h, o[dt], 0, 0, 0);
    }
#pragma unroll
    for (int dt = 0; dt < 8; ++dt) {
      half8 vb = *(const half8*)(Vlds + (dt * 32 + ln) * 80 + 32 + 16 * g);
      o[dt] = __builtin_amdgcn_mfma_f32_32x32x16_f16(vb, f1.h, o[dt], 0, 0, 0);
    }
    cur ^= 1;
  }

  // ---- epilogue: normalize (/l and post-softmax /8), transpose via LDS, 4x tiled store
  float inv = 1.0f / (l_r * 8.0f);
  float* chunk = (float*)smem;    // [32 q][33 d] fp32 (buf0 K region, all DMA drained)
  float* ob = out + ((size_t)(b * T_ + q0)) * 1024;
#pragma unroll
  for (int dt = 0; dt < 8; ++dt) {
    WAIT_LGKM0();                 // prior chunk reads done before overwrite
#pragma unroll
    for (int r = 0; r < 16; ++r) {
      int dl = (r & 3) + 8 * (r >> 2) + 4 * g;
      chunk[ln * 33 + dl] = o[dt][r] * inv;
    }
    WAIT_LGKM0();                 // writes complete -> cross-lane visible
#pragma unroll
    for (int rr = 0; rr < 2; ++rr) {
      int qq = (l >> 2) + 16 * rr;
      int cp = (l & 3) * 8;
      float vv[8];
#pragma unroll
      for (int jj = 0; jj < 8; ++jj) vv[jj] = chunk[qq * 33 + cp + jj];
      float4 w0 = make_float4(vv[0], vv[1], vv[2], vv[3]);
      float4 w1 = make_float4(vv[4], vv[5], vv[6], vv[7]);
      float* orow = ob + (size_t)qq * 1024 + dt * 32 + cp;
#pragma unroll
      for (int rep = 0; rep < 4; ++rep) {
        *(float4*)(orow + rep * 256)     = w0;
        *(float4*)(orow + rep * 256 + 4) = w1;
      }
    }
  }
}

extern "C" void kernel_launch(void* const* d_in, const int* in_sizes, int n_in,
                              void* d_out, int out_size, void* d_ws, size_t ws_size,
                              hipStream_t stream) {
  const float* x  = (const float*)d_in[0];
  const float* Wq = (const float*)d_in[1];
  const float* bq = (const float*)d_in[2];
  const float* Wk = (const float*)d_in[3];
  const float* bk = (const float*)d_in[4];
  const float* Wv = (const float*)d_in[5];
  const float* bv = (const float*)d_in[6];
  float* out = (float*)d_out;
  char* ws = (char*)d_ws;
  float* Wqf = (float*)ws;                               // 1 MB
  float* bqf = (float*)(ws + (1 << 20));                 // 1 KB (padded)
  _Float16* Qh = (_Float16*)(ws + (1 << 20) + 4096);     // 8 MB
  _Float16* Kh = Qh + (size_t)16384 * 256;               // 8 MB
  _Float16* Vt = Kh + (size_t)16384 * 256;               // 8 MB

  fold_wq<<<1024, 256, 0, stream>>>(Wq, bq, Wqf, bqf);
  proj_gemm<<<dim3(128, 12), 256, 0, stream>>>(x, Wqf, bqf, Wk, bk, Wv, bv, Qh, Kh, Vt);
  attn_mfma<<<512, 64, 0, stream>>>(Qh, Kh, Vt, out);
}

// Round 5
// 205.327 us; speedup vs baseline: 8.0022x; 2.3097x over previous
//
#include <hip/hip_runtime.h>
#include <float.h>
#include <stdint.h>

#define T_ 2048
#define DG 256   // folded/group width: 4 groups * 64

typedef _Float16 half8 __attribute__((ext_vector_type(8)));
typedef _Float16 half4v __attribute__((ext_vector_type(4)));
typedef __fp16 fp16x2 __attribute__((ext_vector_type(2)));
typedef float f32x4 __attribute__((ext_vector_type(4)));
typedef float f32x16 __attribute__((ext_vector_type(16)));

__device__ __forceinline__ void gload16(const void* g, void* l) {
  __builtin_amdgcn_global_load_lds(
      (const __attribute__((address_space(1))) unsigned int*)g,
      (__attribute__((address_space(3))) unsigned int*)l, 16, 0, 0);
}
#define WAIT_VM0()   do { asm volatile("s_waitcnt vmcnt(0)" ::: "memory"); __builtin_amdgcn_sched_barrier(0); } while (0)
#define WAIT_LGKM0() do { asm volatile("s_waitcnt lgkmcnt(0)" ::: "memory"); __builtin_amdgcn_sched_barrier(0); } while (0)

// ---- prep_w: Wt[768][1024] fp16 (folded Wq | Wk | Wv, transposed) + bcat[768] f32 ----
__global__ __launch_bounds__(256) void prep_w(
    const float* __restrict__ Wq, const float* __restrict__ bq,
    const float* __restrict__ Wk, const float* __restrict__ bk,
    const float* __restrict__ Wv, const float* __restrict__ bv,
    _Float16* __restrict__ Wt, float* __restrict__ bcat) {
  int idx = blockIdx.x * 256 + threadIdx.x;   // 786432
  int n = idx >> 10, k = idx & 1023;
  float v;
  if (n < 256)      v = Wq[k * 1024 + n] + Wq[k * 1024 + n + 256]
                      + Wq[k * 1024 + n + 512] + Wq[k * 1024 + n + 768];
  else if (n < 512) v = Wk[k * 256 + n - 256];
  else              v = Wv[k * 256 + n - 512];
  Wt[idx] = (_Float16)v;
  if (k == 0) {
    float bb;
    if (n < 256)      bb = bq[n] + bq[n + 256] + bq[n + 512] + bq[n + 768];
    else if (n < 512) bb = bk[n - 256];
    else              bb = bv[n - 512];
    bcat[n] = bb;
  }
}

// ---- qkv_gemm: [16384 x 1024] fp32 x @ Wt^T -> Q fp16(x log2e) | K fp16 | V^T fp16 ----
// 128x128 tile, 4 waves, mfma_f32_16x16x32_f16, A staged fp32 (convert at frag read),
// B staged fp16 via global_load_lds; XOR-swizzled LDS rows (2-way conflicts = free).
__global__ __launch_bounds__(256) void qkv_gemm(
    const float* __restrict__ x, const _Float16* __restrict__ Wt,
    const float* __restrict__ bcat,
    _Float16* __restrict__ Qh, _Float16* __restrict__ Kh, _Float16* __restrict__ Vt) {
  __shared__ __align__(16) uint8_t smem[49152];   // 2 x (A 16KB fp32 + B 8KB fp16)
  const int tid = threadIdx.x;
  const int w = tid >> 6, l = tid & 63;
  const int wr = w >> 1, wc = w & 1;
  const int lr = l & 15, lk = l >> 4;             // frag row / k-slot
  const int m0 = blockIdx.x * 128, n0 = blockIdx.y * 128;

  f32x4 acc[4][4] = {};

  auto stage = [&](int k0, int buf) {
    uint8_t* Ab = smem + buf * 24576;
    uint8_t* Bb = Ab + 16384;
    // A: 128 rows x 32 fp32 = 1024 slots of 16B; logical slot at phys p holds col (p^(row&7))
#pragma unroll
    for (int i = 0; i < 4; ++i) {
      int si = i * 256 + tid;
      int row = si >> 3, p = si & 7;
      gload16(x + (size_t)(m0 + row) * 1024 + k0 + ((p ^ (row & 7)) << 2), Ab + si * 16);
    }
    // B: 128 rows x 32 fp16 = 512 slots of 16B; phys p holds col-slot (p^(row&3))
#pragma unroll
    for (int i = 0; i < 2; ++i) {
      int si = i * 256 + tid;
      int row = si >> 2, p = si & 3;
      gload16(Wt + (size_t)(n0 + row) * 1024 + k0 + ((p ^ (row & 3)) << 3), Bb + si * 16);
    }
  };

  stage(0, 0);
  __syncthreads();   // drains vmcnt before barrier

  for (int kt = 0; kt < 32; ++kt) {
    int cur = kt & 1;
    if (kt < 31) stage((kt + 1) * 32, cur ^ 1);
    const uint8_t* Ab = smem + cur * 24576;
    const uint8_t* Bb = Ab + 16384;
    half8 af[4], bf[4];
#pragma unroll
    for (int mi = 0; mi < 4; ++mi) {
      int row = wr * 64 + mi * 16 + lr;
      const float* pa = (const float*)(Ab + row * 128);
      f32x4 a0 = *(const f32x4*)(pa + ((((lk << 1))     ^ (row & 7)) << 2));
      f32x4 a1 = *(const f32x4*)(pa + ((((lk << 1) | 1) ^ (row & 7)) << 2));
      half8 h;
#pragma unroll
      for (int j = 0; j < 4; ++j) { h[j] = (_Float16)a0[j]; h[j + 4] = (_Float16)a1[j]; }
      af[mi] = h;
    }
#pragma unroll
    for (int ni = 0; ni < 4; ++ni) {
      int row = wc * 64 + ni * 16 + lr;
      bf[ni] = *(const half8*)(Bb + row * 64 + ((lk ^ (row & 3)) << 4));
    }
#pragma unroll
    for (int mi = 0; mi < 4; ++mi)
#pragma unroll
      for (int ni = 0; ni < 4; ++ni)
        acc[mi][ni] = __builtin_amdgcn_mfma_f32_16x16x32_f16(af[mi], bf[ni], acc[mi][ni], 0, 0, 0);
    __syncthreads();
  }

  // ---- epilogue: C col = lane&15 (n), row = (lane>>4)*4 + r (m)  [m89-verified] ----
#pragma unroll
  for (int mi = 0; mi < 4; ++mi) {
#pragma unroll
    for (int ni = 0; ni < 4; ++ni) {
      int ng = n0 + wc * 64 + ni * 16 + lr;
      int mg = m0 + wr * 64 + mi * 16 + lk * 4;
      float bias = bcat[ng];
      if (ng < 256) {
#pragma unroll
        for (int r = 0; r < 4; ++r)
          Qh[(size_t)(mg + r) * DG + ng] = (_Float16)((acc[mi][ni][r] + bias) * 1.44269504f);
      } else if (ng < 512) {
#pragma unroll
        for (int r = 0; r < 4; ++r)
          Kh[(size_t)(mg + r) * DG + (ng - 256)] = (_Float16)(acc[mi][ni][r] + bias);
      } else {
        half4v h;
#pragma unroll
        for (int r = 0; r < 4; ++r) h[r] = (_Float16)(acc[mi][ni][r] + bias);
        *(half4v*)(Vt + ((size_t)((mg >> 11) * DG + (ng - 512))) * T_ + (mg & 2047)) = h;
      }
    }
  }
}

// ---------------- fused causal attention, swapped-operand MFMA, fp16 ----------------
__global__ __launch_bounds__(64, 1) void attn_mfma(
    const _Float16* __restrict__ Qg, const _Float16* __restrict__ Kg,
    const _Float16* __restrict__ Vtg, float* __restrict__ out) {
  __shared__ __align__(16) uint8_t smem[73728];   // 2 x (16KB K + 20KB V)
  const int l  = threadIdx.x;
  const int g  = l >> 5;
  const int ln = l & 31;
  const int bid = blockIdx.x;
  const int b   = bid & 7;                 // batch -> XCD pinning
  // load-balance: bid c and c+256 land on the same CU; pair long+short tiles (sum=65)
  const int tile = (bid < 256) ? (63 - (bid >> 3)) : ((bid - 256) >> 3);
  const int q0 = tile * 32;

  const _Float16* Qrow = Qg + ((size_t)(b * T_ + q0 + ln)) * DG + 8 * g;
  half8 qf[16];
#pragma unroll
  for (int kk = 0; kk < 16; ++kk) qf[kk] = *(const half8*)(Qrow + kk * 16);

  f32x16 o[8] = {};
  float m_r = -1e30f, l_r = 0.0f;

  auto stage = [&](int s0, int buf) {
    uint8_t* Kl = smem + buf * 36864;
    uint8_t* Vl = Kl + 16384;
#pragma unroll
    for (int i = 0; i < 16; ++i) {
      int slot = i * 64 + l;
      int row = slot >> 5, part = slot & 31;
      const _Float16* src = Kg + ((size_t)(b * T_ + s0 + row)) * DG + ((part ^ (row & 7)) << 3);
      gload16(src, Kl + i * 1024);
    }
#pragma unroll
    for (int i = 0; i < 20; ++i) {
      int slot = i * 64 + l;
      int d = slot / 5, part = slot - d * 5;
      int sp = (part < 4) ? (part << 3) : 0;
      const _Float16* src = Vtg + ((size_t)(b * DG + d)) * T_ + s0 + sp;
      gload16(src, Vl + i * 1024);
    }
  };

  stage(0, 0);
  int cur = 0;

  for (int kt = 0; kt <= tile; ++kt) {
    WAIT_VM0();
    if (kt < tile) stage((kt + 1) * 32, cur ^ 1);
    uint8_t* Klds = smem + cur * 36864;
    uint8_t* Vlds = Klds + 16384;

    f32x16 sa = {}, sb = {};
    const int xr = (ln & 7) << 4;
#pragma unroll
    for (int kk = 0; kk < 16; kk += 2) {
      half8 ka = *(const half8*)(Klds + ln * 512 + ((kk * 32 + 16 * g) ^ xr));
      half8 kb = *(const half8*)(Klds + ln * 512 + (((kk + 1) * 32 + 16 * g) ^ xr));
      sa = __builtin_amdgcn_mfma_f32_32x32x16_f16(ka, qf[kk],     sa, 0, 0, 0);
      sb = __builtin_amdgcn_mfma_f32_32x32x16_f16(kb, qf[kk + 1], sb, 0, 0, 0);
    }
    float s[16];
#pragma unroll
    for (int r = 0; r < 16; ++r) s[r] = sa[r] + sb[r];
    if (kt == tile) {
#pragma unroll
      for (int r = 0; r < 16; ++r) {
        int srow = (r & 3) + 8 * (r >> 2) + 4 * g;
        if (srow > ln) s[r] = -1e30f;
      }
    }
    float pmax = s[0];
#pragma unroll
    for (int r = 1; r < 16; ++r) pmax = fmaxf(pmax, s[r]);
    pmax = fmaxf(pmax, __shfl_xor(pmax, 32));
    if (!__all(pmax <= m_r + 8.0f)) {
      float mnew = fmaxf(m_r, pmax);
      float sc = exp2f(m_r - mnew);
      l_r *= sc;
#pragma unroll
      for (int dt = 0; dt < 8; ++dt)
#pragma unroll
        for (int r = 0; r < 16; ++r) o[dt][r] *= sc;
      m_r = mnew;
    }
    float p[16]; float psum = 0.0f;
#pragma unroll
    for (int r = 0; r < 16; ++r) { p[r] = exp2f(s[r] - m_r); psum += p[r]; }
    l_r += psum + __shfl_xor(psum, 32);

    unsigned ph[8], xh[8];
#pragma unroll
    for (int i = 0; i < 8; ++i) {
      fp16x2 t2 = __builtin_amdgcn_cvt_pkrtz(p[2 * i], p[2 * i + 1]);
      ph[i] = __builtin_bit_cast(unsigned, t2);
      xh[i] = (unsigned)__shfl_xor((int)ph[i], 32);
    }
    union U { unsigned u[4]; half8 h; };
    U f0, f1;
    f0.u[0] = g ? xh[2] : ph[0]; f0.u[1] = g ? xh[3] : ph[1];
    f0.u[2] = g ? ph[2] : xh[0]; f0.u[3] = g ? ph[3] : xh[1];
    f1.u[0] = g ? xh[6] : ph[4]; f1.u[1] = g ? xh[7] : ph[5];
    f1.u[2] = g ? ph[6] : xh[4]; f1.u[3] = g ? ph[7] : xh[5];

#pragma unroll
    for (int dt = 0; dt < 8; ++dt) {
      half8 va = *(const half8*)(Vlds + (dt * 32 + ln) * 80 + 16 * g);
      o[dt] = __builtin_amdgcn_mfma_f32_32x32x16_f16(va, f0.h, o[dt], 0, 0, 0);
    }
#pragma unroll
    for (int dt = 0; dt < 8; ++dt) {
      half8 vb = *(const half8*)(Vlds + (dt * 32 + ln) * 80 + 32 + 16 * g);
      o[dt] = __builtin_amdgcn_mfma_f32_32x32x16_f16(vb, f1.h, o[dt], 0, 0, 0);
    }
    cur ^= 1;
  }

  float inv = 1.0f / (l_r * 8.0f);
  float* chunk = (float*)smem;
  float* ob = out + ((size_t)(b * T_ + q0)) * 1024;
#pragma unroll
  for (int dt = 0; dt < 8; ++dt) {
    WAIT_LGKM0();
#pragma unroll
    for (int r = 0; r < 16; ++r) {
      int dl = (r & 3) + 8 * (r >> 2) + 4 * g;
      chunk[ln * 33 + dl] = o[dt][r] * inv;
    }
    WAIT_LGKM0();
#pragma unroll
    for (int rr = 0; rr < 2; ++rr) {
      int qq = (l >> 2) + 16 * rr;
      int cp = (l & 3) * 8;
      float vv[8];
#pragma unroll
      for (int jj = 0; jj < 8; ++jj) vv[jj] = chunk[qq * 33 + cp + jj];
      float4 w0 = make_float4(vv[0], vv[1], vv[2], vv[3]);
      float4 w1 = make_float4(vv[4], vv[5], vv[6], vv[7]);
      float* orow = ob + (size_t)qq * 1024 + dt * 32 + cp;
#pragma unroll
      for (int rep = 0; rep < 4; ++rep) {
        *(float4*)(orow + rep * 256)     = w0;
        *(float4*)(orow + rep * 256 + 4) = w1;
      }
    }
  }
}

extern "C" void kernel_launch(void* const* d_in, const int* in_sizes, int n_in,
                              void* d_out, int out_size, void* d_ws, size_t ws_size,
                              hipStream_t stream) {
  const float* x  = (const float*)d_in[0];
  const float* Wq = (const float*)d_in[1];
  const float* bq = (const float*)d_in[2];
  const float* Wk = (const float*)d_in[3];
  const float* bk = (const float*)d_in[4];
  const float* Wv = (const float*)d_in[5];
  const float* bv = (const float*)d_in[6];
  float* out = (float*)d_out;
  char* ws = (char*)d_ws;
  _Float16* Wt   = (_Float16*)ws;                         // 1.5 MB
  float*    bcat = (float*)(ws + 0x180000);               // 3 KB (pad to 4 KB)
  _Float16* Qh   = (_Float16*)(ws + 0x181000);            // 8 MB
  _Float16* Kh   = Qh + (size_t)16384 * 256;              // 8 MB
  _Float16* Vt   = Kh + (size_t)16384 * 256;              // 8 MB  (total ~25.6 MB)

  prep_w<<<3072, 256, 0, stream>>>(Wq, bq, Wk, bk, Wv, bv, Wt, bcat);
  qkv_gemm<<<dim3(128, 6), 256, 0, stream>>>(x, Wt, bcat, Qh, Kh, Vt);
  attn_mfma<<<512, 64, 0, stream>>>(Qh, Kh, Vt, out);
}

// Round 6
// 157.667 us; speedup vs baseline: 10.4211x; 1.3023x over previous
//
#include <hip/hip_runtime.h>
#include <float.h>
#include <stdint.h>

#define T_ 2048
#define DG 256   // folded/group width: 4 groups * 64

typedef _Float16 half8 __attribute__((ext_vector_type(8)));
typedef _Float16 half4v __attribute__((ext_vector_type(4)));
typedef __fp16 fp16x2 __attribute__((ext_vector_type(2)));
typedef float f32x4 __attribute__((ext_vector_type(4)));
typedef float f32x16 __attribute__((ext_vector_type(16)));

__device__ __forceinline__ void gload16(const void* g, void* l) {
  __builtin_amdgcn_global_load_lds(
      (const __attribute__((address_space(1))) unsigned int*)g,
      (__attribute__((address_space(3))) unsigned int*)l, 16, 0, 0);
}
#define WAIT_VM0()   do { asm volatile("s_waitcnt vmcnt(0)" ::: "memory"); __builtin_amdgcn_sched_barrier(0); } while (0)
#define WAIT_LGKM0() do { asm volatile("s_waitcnt lgkmcnt(0)" ::: "memory"); __builtin_amdgcn_sched_barrier(0); } while (0)

// ---- prep_w: Wt[768][1024] fp16 (folded Wq | Wk | Wv, transposed) + bcat[768] f32 ----
__global__ __launch_bounds__(256) void prep_w(
    const float* __restrict__ Wq, const float* __restrict__ bq,
    const float* __restrict__ Wk, const float* __restrict__ bk,
    const float* __restrict__ Wv, const float* __restrict__ bv,
    _Float16* __restrict__ Wt, float* __restrict__ bcat) {
  int idx = blockIdx.x * 256 + threadIdx.x;   // 786432
  int n = idx >> 10, k = idx & 1023;
  float v;
  if (n < 256)      v = Wq[k * 1024 + n] + Wq[k * 1024 + n + 256]
                      + Wq[k * 1024 + n + 512] + Wq[k * 1024 + n + 768];
  else if (n < 512) v = Wk[k * 256 + n - 256];
  else              v = Wv[k * 256 + n - 512];
  Wt[idx] = (_Float16)v;
  if (k == 0) {
    float bb;
    if (n < 256)      bb = bq[n] + bq[n + 256] + bq[n + 512] + bq[n + 768];
    else if (n < 512) bb = bk[n - 256];
    else              bb = bv[n - 512];
    bcat[n] = bb;
  }
}

// ---- qkv_gemm: [16384 x 1024] fp32 x @ Wt^T -> Q fp16(x log2e) | K fp16 | V^T fp16 ----
__global__ __launch_bounds__(256) void qkv_gemm(
    const float* __restrict__ x, const _Float16* __restrict__ Wt,
    const float* __restrict__ bcat,
    _Float16* __restrict__ Qh, _Float16* __restrict__ Kh, _Float16* __restrict__ Vt) {
  __shared__ __align__(16) uint8_t smem[49152];   // 2 x (A 16KB fp32 + B 8KB fp16)
  const int tid = threadIdx.x;
  const int w = tid >> 6, l = tid & 63;
  const int wr = w >> 1, wc = w & 1;
  const int lr = l & 15, lk = l >> 4;
  const int m0 = blockIdx.x * 128, n0 = blockIdx.y * 128;

  f32x4 acc[4][4] = {};

  auto stage = [&](int k0, int buf) {
    uint8_t* Ab = smem + buf * 24576;
    uint8_t* Bb = Ab + 16384;
#pragma unroll
    for (int i = 0; i < 4; ++i) {
      int si = i * 256 + tid;
      int row = si >> 3, p = si & 7;
      gload16(x + (size_t)(m0 + row) * 1024 + k0 + ((p ^ (row & 7)) << 2), Ab + si * 16);
    }
#pragma unroll
    for (int i = 0; i < 2; ++i) {
      int si = i * 256 + tid;
      int row = si >> 2, p = si & 3;
      gload16(Wt + (size_t)(n0 + row) * 1024 + k0 + ((p ^ (row & 3)) << 3), Bb + si * 16);
    }
  };

  stage(0, 0);
  __syncthreads();

  for (int kt = 0; kt < 32; ++kt) {
    int cur = kt & 1;
    if (kt < 31) stage((kt + 1) * 32, cur ^ 1);
    const uint8_t* Ab = smem + cur * 24576;
    const uint8_t* Bb = Ab + 16384;
    half8 af[4], bf[4];
#pragma unroll
    for (int mi = 0; mi < 4; ++mi) {
      int row = wr * 64 + mi * 16 + lr;
      const float* pa = (const float*)(Ab + row * 128);
      f32x4 a0 = *(const f32x4*)(pa + ((((lk << 1))     ^ (row & 7)) << 2));
      f32x4 a1 = *(const f32x4*)(pa + ((((lk << 1) | 1) ^ (row & 7)) << 2));
      half8 h;
#pragma unroll
      for (int j = 0; j < 4; ++j) { h[j] = (_Float16)a0[j]; h[j + 4] = (_Float16)a1[j]; }
      af[mi] = h;
    }
#pragma unroll
    for (int ni = 0; ni < 4; ++ni) {
      int row = wc * 64 + ni * 16 + lr;
      bf[ni] = *(const half8*)(Bb + row * 64 + ((lk ^ (row & 3)) << 4));
    }
#pragma unroll
    for (int mi = 0; mi < 4; ++mi)
#pragma unroll
      for (int ni = 0; ni < 4; ++ni)
        acc[mi][ni] = __builtin_amdgcn_mfma_f32_16x16x32_f16(af[mi], bf[ni], acc[mi][ni], 0, 0, 0);
    __syncthreads();
  }

#pragma unroll
  for (int mi = 0; mi < 4; ++mi) {
#pragma unroll
    for (int ni = 0; ni < 4; ++ni) {
      int ng = n0 + wc * 64 + ni * 16 + lr;
      int mg = m0 + wr * 64 + mi * 16 + lk * 4;
      float bias = bcat[ng];
      if (ng < 256) {
#pragma unroll
        for (int r = 0; r < 4; ++r)
          Qh[(size_t)(mg + r) * DG + ng] = (_Float16)((acc[mi][ni][r] + bias) * 1.44269504f);
      } else if (ng < 512) {
#pragma unroll
        for (int r = 0; r < 4; ++r)
          Kh[(size_t)(mg + r) * DG + (ng - 256)] = (_Float16)(acc[mi][ni][r] + bias);
      } else {
        half4v h;
#pragma unroll
        for (int r = 0; r < 4; ++r) h[r] = (_Float16)(acc[mi][ni][r] + bias);
        *(half4v*)(Vt + ((size_t)((mg >> 11) * DG + (ng - 512))) * T_ + (mg & 2047)) = h;
      }
    }
  }
}

// ---------------- fused causal attention: 2 waves/WG, KV-split, LDS merge ----------------
// Wave w scans KV tiles w, w+2, ... with its own partial (m,l,o); merged at the end.
// K double-buffered in LDS (per-wave region); V fragments read direct from L2.
__global__ __launch_bounds__(128, 1) void attn_mfma(
    const _Float16* __restrict__ Qg, const _Float16* __restrict__ Kg,
    const _Float16* __restrict__ Vtg, float* __restrict__ out) {
  __shared__ __align__(16) uint8_t smem[65536];   // [wv*32768 + buf*16384] K bufs
  const int tid = threadIdx.x;
  const int wv = tid >> 6;        // 0/1
  const int l  = tid & 63;
  const int g  = l >> 5;
  const int ln = l & 31;
  const int bid = blockIdx.x;
  const int b   = bid & 7;                 // batch -> XCD pinning
  const int tile = (bid < 256) ? (63 - (bid >> 3)) : ((bid - 256) >> 3);
  const int q0 = tile * 32;

  const _Float16* Kb = Kg  + (size_t)b * T_ * DG;
  const _Float16* Vb = Vtg + (size_t)b * DG * T_;

  const _Float16* Qrow = Qg + ((size_t)(b * T_ + q0 + ln)) * DG + 8 * g;
  half8 qf[16];
#pragma unroll
  for (int kk = 0; kk < 16; ++kk) qf[kk] = *(const half8*)(Qrow + kk * 16);

  f32x16 o[8] = {};
  float m_r = -1e30f, l_r = 0.0f;

  uint8_t* myK = smem + wv * 32768;
  auto stageK = [&](int s0, int buf) {
    uint8_t* Kl = myK + buf * 16384;
#pragma unroll
    for (int i = 0; i < 16; ++i) {
      int slot = i * 64 + l;
      int row = slot >> 5, part = slot & 31;
      gload16(Kb + (size_t)(s0 + row) * DG + ((part ^ (row & 7)) << 3), Kl + i * 1024);
    }
  };

  int cur = 0;
  if (wv <= tile) stageK(wv * 32, 0);

  for (int kt = wv; kt <= tile; kt += 2) {
    WAIT_VM0();                      // K buf `cur` staged
    int s0 = kt * 32;
    // V fragments direct from global (L2-resident): A[row=dt*32+ln][k=8g+j]
    half8 vf0[8], vf1[8];
#pragma unroll
    for (int dt = 0; dt < 8; ++dt) {
      const _Float16* vr = Vb + (size_t)(dt * 32 + ln) * T_ + s0 + 8 * g;
      vf0[dt] = *(const half8*)vr;
      vf1[dt] = *(const half8*)(vr + 16);
    }
    if (kt + 2 <= tile) stageK((kt + 2) * 32, cur ^ 1);
    uint8_t* Klds = myK + cur * 16384;

    f32x16 sa = {}, sb = {};
    const int xr = (ln & 7) << 4;
#pragma unroll
    for (int kk = 0; kk < 16; kk += 2) {
      half8 ka = *(const half8*)(Klds + ln * 512 + ((kk * 32 + 16 * g) ^ xr));
      half8 kb = *(const half8*)(Klds + ln * 512 + (((kk + 1) * 32 + 16 * g) ^ xr));
      sa = __builtin_amdgcn_mfma_f32_32x32x16_f16(ka, qf[kk],     sa, 0, 0, 0);
      sb = __builtin_amdgcn_mfma_f32_32x32x16_f16(kb, qf[kk + 1], sb, 0, 0, 0);
    }
    float s[16];
#pragma unroll
    for (int r = 0; r < 16; ++r) s[r] = sa[r] + sb[r];
    if (kt == tile) {                // causal mask, diagonal tile only
#pragma unroll
      for (int r = 0; r < 16; ++r) {
        int srow = (r & 3) + 8 * (r >> 2) + 4 * g;
        if (srow > ln) s[r] = -1e30f;
      }
    }
    float pmax = s[0];
#pragma unroll
    for (int r = 1; r < 16; ++r) pmax = fmaxf(pmax, s[r]);
    pmax = fmaxf(pmax, __shfl_xor(pmax, 32));
    if (!__all(pmax <= m_r + 8.0f)) {   // defer-max rescale (T13)
      float mnew = fmaxf(m_r, pmax);
      float sc = exp2f(m_r - mnew);
      l_r *= sc;
#pragma unroll
      for (int dt = 0; dt < 8; ++dt)
#pragma unroll
        for (int r = 0; r < 16; ++r) o[dt][r] *= sc;
      m_r = mnew;
    }
    float p[16]; float psum = 0.0f;
#pragma unroll
    for (int r = 0; r < 16; ++r) { p[r] = exp2f(s[r] - m_r); psum += p[r]; }
    l_r += psum + __shfl_xor(psum, 32);

    unsigned ph[8], xh[8];
#pragma unroll
    for (int i = 0; i < 8; ++i) {
      fp16x2 t2 = __builtin_amdgcn_cvt_pkrtz(p[2 * i], p[2 * i + 1]);
      ph[i] = __builtin_bit_cast(unsigned, t2);
      xh[i] = (unsigned)__shfl_xor((int)ph[i], 32);
    }
    union U { unsigned u[4]; half8 h; };
    U f0, f1;
    f0.u[0] = g ? xh[2] : ph[0]; f0.u[1] = g ? xh[3] : ph[1];
    f0.u[2] = g ? ph[2] : xh[0]; f0.u[3] = g ? ph[3] : xh[1];
    f1.u[0] = g ? xh[6] : ph[4]; f1.u[1] = g ? xh[7] : ph[5];
    f1.u[2] = g ? ph[6] : xh[4]; f1.u[3] = g ? ph[7] : xh[5];

#pragma unroll
    for (int dt = 0; dt < 8; ++dt)
      o[dt] = __builtin_amdgcn_mfma_f32_32x32x16_f16(vf0[dt], f0.h, o[dt], 0, 0, 0);
#pragma unroll
    for (int dt = 0; dt < 8; ++dt)
      o[dt] = __builtin_amdgcn_mfma_f32_32x32x16_f16(vf1[dt], f1.h, o[dt], 0, 0, 0);
    cur ^= 1;
  }

  // ---- merge wave1's partial into wave0, then epilogue (wave0 only) ----
  __syncthreads();
  if (wv == 1) {
    float* dst = (float*)(smem + 32768);   // [128][64]: idx-major, lane-minor (conflict-free)
#pragma unroll
    for (int dt = 0; dt < 8; ++dt)
#pragma unroll
      for (int r = 0; r < 16; ++r)
        dst[(dt * 16 + r) * 64 + l] = o[dt][r];
    ((float*)smem)[l]      = m_r;
    ((float*)smem)[64 + l] = l_r;
  }
  __syncthreads();
  if (wv == 0) {
    float m1 = ((float*)smem)[l];
    float l1 = ((float*)smem)[64 + l];
    float M   = fmaxf(m_r, m1);
    float sc0 = exp2f(m_r - M);
    float sc1 = exp2f(m1 - M);
    float lt  = l_r * sc0 + l1 * sc1;
    float inv = 1.0f / (lt * 8.0f);      // includes post-softmax /sqrt(64)
    const float* src = (const float*)(smem + 32768);
    float* chunk = (float*)(smem + 4096);   // [32 q][33 d] fp32
    float* ob = out + ((size_t)(b * T_ + q0)) * 1024;
#pragma unroll
    for (int dt = 0; dt < 8; ++dt) {
      WAIT_LGKM0();
#pragma unroll
      for (int r = 0; r < 16; ++r) {
        int dl = (r & 3) + 8 * (r >> 2) + 4 * g;
        float merged = (o[dt][r] * sc0 + src[(dt * 16 + r) * 64 + l] * sc1) * inv;
        chunk[ln * 33 + dl] = merged;
      }
      WAIT_LGKM0();
#pragma unroll
      for (int rr = 0; rr < 2; ++rr) {
        int qq = (l >> 2) + 16 * rr;
        int cp = (l & 3) * 8;
        float vv[8];
#pragma unroll
        for (int jj = 0; jj < 8; ++jj) vv[jj] = chunk[qq * 33 + cp + jj];
        float4 w0 = make_float4(vv[0], vv[1], vv[2], vv[3]);
        float4 w1 = make_float4(vv[4], vv[5], vv[6], vv[7]);
        float* orow = ob + (size_t)qq * 1024 + dt * 32 + cp;
#pragma unroll
        for (int rep = 0; rep < 4; ++rep) {
          *(float4*)(orow + rep * 256)     = w0;
          *(float4*)(orow + rep * 256 + 4) = w1;
        }
      }
    }
  }
}

extern "C" void kernel_launch(void* const* d_in, const int* in_sizes, int n_in,
                              void* d_out, int out_size, void* d_ws, size_t ws_size,
                              hipStream_t stream) {
  const float* x  = (const float*)d_in[0];
  const float* Wq = (const float*)d_in[1];
  const float* bq = (const float*)d_in[2];
  const float* Wk = (const float*)d_in[3];
  const float* bk = (const float*)d_in[4];
  const float* Wv = (const float*)d_in[5];
  const float* bv = (const float*)d_in[6];
  float* out = (float*)d_out;
  char* ws = (char*)d_ws;
  _Float16* Wt   = (_Float16*)ws;                         // 1.5 MB
  float*    bcat = (float*)(ws + 0x180000);               // 3 KB (pad to 4 KB)
  _Float16* Qh   = (_Float16*)(ws + 0x181000);            // 8 MB
  _Float16* Kh   = Qh + (size_t)16384 * 256;              // 8 MB
  _Float16* Vt   = Kh + (size_t)16384 * 256;              // 8 MB  (total ~25.6 MB)

  prep_w<<<3072, 256, 0, stream>>>(Wq, bq, Wk, bk, Wv, bv, Wt, bcat);
  qkv_gemm<<<dim3(128, 6), 256, 0, stream>>>(x, Wt, bcat, Qh, Kh, Vt);
  attn_mfma<<<512, 128, 0, stream>>>(Qh, Kh, Vt, out);
}

// Round 7
// 136.476 us; speedup vs baseline: 12.0393x; 1.1553x over previous
//
#include <hip/hip_runtime.h>
#include <float.h>
#include <stdint.h>

#define T_ 2048
#define DG 256   // folded/group width: 4 groups * 64

typedef _Float16 half8 __attribute__((ext_vector_type(8)));
typedef _Float16 half4v __attribute__((ext_vector_type(4)));
typedef __fp16 fp16x2 __attribute__((ext_vector_type(2)));
typedef float f32x4 __attribute__((ext_vector_type(4)));
typedef float f32x16 __attribute__((ext_vector_type(16)));
typedef unsigned uint2v __attribute__((ext_vector_type(2)));

__device__ __forceinline__ void gload16(const void* g, void* l) {
  __builtin_amdgcn_global_load_lds(
      (const __attribute__((address_space(1))) unsigned int*)g,
      (__attribute__((address_space(3))) unsigned int*)l, 16, 0, 0);
}
#define WAIT_VMC(N)  do { asm volatile("s_waitcnt vmcnt(" #N ")" ::: "memory"); __builtin_amdgcn_sched_barrier(0); } while (0)
#define WAIT_LGKM0() do { asm volatile("s_waitcnt lgkmcnt(0)" ::: "memory"); __builtin_amdgcn_sched_barrier(0); } while (0)

// lane<->lane^32 exchange, all-VALU (v_permlane32_swap_b32)
__device__ __forceinline__ float cross32(float x, int g) {
  unsigned u = __builtin_bit_cast(unsigned, x);
  uint2v r = __builtin_amdgcn_permlane32_swap(u, u, false, false);
  return __builtin_bit_cast(float, g ? r[0] : r[1]);
}

// ---- prep_w: Wt[768][1024] fp16 (folded Wq | Wk | Wv, transposed) + bcat[768] f32 ----
__global__ __launch_bounds__(256) void prep_w(
    const float* __restrict__ Wq, const float* __restrict__ bq,
    const float* __restrict__ Wk, const float* __restrict__ bk,
    const float* __restrict__ Wv, const float* __restrict__ bv,
    _Float16* __restrict__ Wt, float* __restrict__ bcat) {
  int idx = blockIdx.x * 256 + threadIdx.x;   // 786432
  int n = idx >> 10, k = idx & 1023;
  float v;
  if (n < 256)      v = Wq[k * 1024 + n] + Wq[k * 1024 + n + 256]
                      + Wq[k * 1024 + n + 512] + Wq[k * 1024 + n + 768];
  else if (n < 512) v = Wk[k * 256 + n - 256];
  else              v = Wv[k * 256 + n - 512];
  Wt[idx] = (_Float16)v;
  if (k == 0) {
    float bb;
    if (n < 256)      bb = bq[n] + bq[n + 256] + bq[n + 512] + bq[n + 768];
    else if (n < 512) bb = bk[n - 256];
    else              bb = bv[n - 512];
    bcat[n] = bb;
  }
}

// ---- qkv_gemm: [16384 x 1024] fp32 x @ Wt^T -> Q fp16(x log2e) | K fp16 | V^T fp16 ----
__global__ __launch_bounds__(256) void qkv_gemm(
    const float* __restrict__ x, const _Float16* __restrict__ Wt,
    const float* __restrict__ bcat,
    _Float16* __restrict__ Qh, _Float16* __restrict__ Kh, _Float16* __restrict__ Vt) {
  __shared__ __align__(16) uint8_t smem[49152];   // 2 x (A 16KB fp32 + B 8KB fp16)
  const int tid = threadIdx.x;
  const int w = tid >> 6, l = tid & 63;
  const int wr = w >> 1, wc = w & 1;
  const int lr = l & 15, lk = l >> 4;
  const int m0 = blockIdx.x * 128, n0 = blockIdx.y * 128;

  f32x4 acc[4][4] = {};

  auto stage = [&](int k0, int buf) {
    uint8_t* Ab = smem + buf * 24576;
    uint8_t* Bb = Ab + 16384;
#pragma unroll
    for (int i = 0; i < 4; ++i) {
      int si = i * 256 + tid;
      int row = si >> 3, p = si & 7;
      gload16(x + (size_t)(m0 + row) * 1024 + k0 + ((p ^ (row & 7)) << 2), Ab + si * 16);
    }
#pragma unroll
    for (int i = 0; i < 2; ++i) {
      int si = i * 256 + tid;
      int row = si >> 2, p = si & 3;
      gload16(Wt + (size_t)(n0 + row) * 1024 + k0 + ((p ^ (row & 3)) << 3), Bb + si * 16);
    }
  };

  stage(0, 0);
  __syncthreads();

  for (int kt = 0; kt < 32; ++kt) {
    int cur = kt & 1;
    if (kt < 31) stage((kt + 1) * 32, cur ^ 1);
    const uint8_t* Ab = smem + cur * 24576;
    const uint8_t* Bb = Ab + 16384;
    half8 af[4], bf[4];
#pragma unroll
    for (int mi = 0; mi < 4; ++mi) {
      int row = wr * 64 + mi * 16 + lr;
      const float* pa = (const float*)(Ab + row * 128);
      f32x4 a0 = *(const f32x4*)(pa + ((((lk << 1))     ^ (row & 7)) << 2));
      f32x4 a1 = *(const f32x4*)(pa + ((((lk << 1) | 1) ^ (row & 7)) << 2));
      half8 h;
#pragma unroll
      for (int j = 0; j < 4; ++j) { h[j] = (_Float16)a0[j]; h[j + 4] = (_Float16)a1[j]; }
      af[mi] = h;
    }
#pragma unroll
    for (int ni = 0; ni < 4; ++ni) {
      int row = wc * 64 + ni * 16 + lr;
      bf[ni] = *(const half8*)(Bb + row * 64 + ((lk ^ (row & 3)) << 4));
    }
#pragma unroll
    for (int mi = 0; mi < 4; ++mi)
#pragma unroll
      for (int ni = 0; ni < 4; ++ni)
        acc[mi][ni] = __builtin_amdgcn_mfma_f32_16x16x32_f16(af[mi], bf[ni], acc[mi][ni], 0, 0, 0);
    __syncthreads();
  }

#pragma unroll
  for (int mi = 0; mi < 4; ++mi) {
#pragma unroll
    for (int ni = 0; ni < 4; ++ni) {
      int ng = n0 + wc * 64 + ni * 16 + lr;
      int mg = m0 + wr * 64 + mi * 16 + lk * 4;
      float bias = bcat[ng];
      if (ng < 256) {
#pragma unroll
        for (int r = 0; r < 4; ++r)
          Qh[(size_t)(mg + r) * DG + ng] = (_Float16)((acc[mi][ni][r] + bias) * 1.44269504f);
      } else if (ng < 512) {
#pragma unroll
        for (int r = 0; r < 4; ++r)
          Kh[(size_t)(mg + r) * DG + (ng - 256)] = (_Float16)(acc[mi][ni][r] + bias);
      } else {
        half4v h;
#pragma unroll
        for (int r = 0; r < 4; ++r) h[r] = (_Float16)(acc[mi][ni][r] + bias);
        *(half4v*)(Vt + ((size_t)((mg >> 11) * DG + (ng - 512))) * T_ + (mg & 2047)) = h;
      }
    }
  }
}

// ---------------- fused causal attention: 2 waves/WG, KV-split, LDS merge ----------------
__global__ __launch_bounds__(128, 1) void attn_mfma(
    const _Float16* __restrict__ Qg, const _Float16* __restrict__ Kg,
    const _Float16* __restrict__ Vtg, float* __restrict__ out) {
  __shared__ __align__(16) uint8_t smem[65536];   // [wv*32768 + buf*16384] K bufs
  const int tid = threadIdx.x;
  const int wv = tid >> 6;        // 0/1
  const int l  = tid & 63;
  const int g  = l >> 5;
  const int ln = l & 31;
  const int bid = blockIdx.x;
  const int b   = bid & 7;                 // batch -> XCD pinning
  const int tile = (bid < 256) ? (63 - (bid >> 3)) : ((bid - 256) >> 3);
  const int q0 = tile * 32;

  const _Float16* Kb = Kg  + (size_t)b * T_ * DG;
  const _Float16* Vb = Vtg + (size_t)b * DG * T_;

  const _Float16* Qrow = Qg + ((size_t)(b * T_ + q0 + ln)) * DG + 8 * g;
  half8 qf[16];
#pragma unroll
  for (int kk = 0; kk < 16; ++kk) qf[kk] = *(const half8*)(Qrow + kk * 16);

  f32x16 o[8] = {};
  float m_r = -1e30f, l_r = 0.0f;

  uint8_t* myK = smem + wv * 32768;
  auto stageK = [&](int s0, int buf) {
    uint8_t* Kl = myK + buf * 16384;
#pragma unroll
    for (int i = 0; i < 16; ++i) {
      int slot = i * 64 + l;
      int row = slot >> 5, part = slot & 31;
      gload16(Kb + (size_t)(s0 + row) * DG + ((part ^ (row & 7)) << 3), Kl + i * 1024);
    }
  };

  int cur = 0;
  if (wv <= tile) stageK(wv * 32, 0);

  for (int kt = wv; kt <= tile; kt += 2) {
    // issue next-tile K stage FIRST (other buffer), then counted wait for cur
    if (kt + 2 <= tile) { stageK((kt + 2) * 32, cur ^ 1); WAIT_VMC(16); }
    else                { WAIT_VMC(0); }
    int s0 = kt * 32;
    uint8_t* Klds = myK + cur * 16384;

    // ---- scores S^T = K . Q^T ----
    f32x16 sa = {}, sb = {};
    const int xr = (ln & 7) << 4;
    __builtin_amdgcn_s_setprio(1);
#pragma unroll
    for (int kk = 0; kk < 16; kk += 2) {
      half8 ka = *(const half8*)(Klds + ln * 512 + ((kk * 32 + 16 * g) ^ xr));
      half8 kb = *(const half8*)(Klds + ln * 512 + (((kk + 1) * 32 + 16 * g) ^ xr));
      sa = __builtin_amdgcn_mfma_f32_32x32x16_f16(ka, qf[kk],     sa, 0, 0, 0);
      sb = __builtin_amdgcn_mfma_f32_32x32x16_f16(kb, qf[kk + 1], sb, 0, 0, 0);
    }
    __builtin_amdgcn_s_setprio(0);

    // V fragments: issue now, consumed after softmax (L2 latency hidden there)
    half8 vf0[8], vf1[8];
#pragma unroll
    for (int dt = 0; dt < 8; ++dt) {
      const _Float16* vr = Vb + (size_t)(dt * 32 + ln) * T_ + s0 + 8 * g;
      vf0[dt] = *(const half8*)vr;
      vf1[dt] = *(const half8*)(vr + 16);
    }

    float s[16];
#pragma unroll
    for (int r = 0; r < 16; ++r) s[r] = sa[r] + sb[r];
    if (kt == tile) {                // causal mask, diagonal tile only
#pragma unroll
      for (int r = 0; r < 16; ++r) {
        int srow = (r & 3) + 8 * (r >> 2) + 4 * g;
        if (srow > ln) s[r] = -1e30f;
      }
    }
    float pmax = s[0];
#pragma unroll
    for (int r = 1; r < 16; ++r) pmax = fmaxf(pmax, s[r]);
    pmax = fmaxf(pmax, cross32(pmax, g));
    if (!__all(pmax <= m_r + 8.0f)) {   // defer-max rescale (T13)
      float mnew = fmaxf(m_r, pmax);
      float sc = __builtin_amdgcn_exp2f(m_r - mnew);
      l_r *= sc;
#pragma unroll
      for (int dt = 0; dt < 8; ++dt)
#pragma unroll
        for (int r = 0; r < 16; ++r) o[dt][r] *= sc;
      m_r = mnew;
    }
    float p[16]; float psum = 0.0f;
#pragma unroll
    for (int r = 0; r < 16; ++r) { p[r] = __builtin_amdgcn_exp2f(s[r] - m_r); psum += p[r]; }
    l_r += psum + cross32(psum, g);

    // ---- P -> fp16 B-fragments: cvt_pkrtz + 4 permlane32_swap (no shuffles) ----
    unsigned ph[8];
#pragma unroll
    for (int i = 0; i < 8; ++i) {
      fp16x2 t2 = __builtin_amdgcn_cvt_pkrtz(p[2 * i], p[2 * i + 1]);
      ph[i] = __builtin_bit_cast(unsigned, t2);
    }
    union U { unsigned u[4]; half8 h; };
    U f0, f1;
    {
      uint2v r02 = __builtin_amdgcn_permlane32_swap(ph[0], ph[2], false, false);
      uint2v r13 = __builtin_amdgcn_permlane32_swap(ph[1], ph[3], false, false);
      uint2v r46 = __builtin_amdgcn_permlane32_swap(ph[4], ph[6], false, false);
      uint2v r57 = __builtin_amdgcn_permlane32_swap(ph[5], ph[7], false, false);
      f0.u[0] = r02[0]; f0.u[2] = r02[1];
      f0.u[1] = r13[0]; f0.u[3] = r13[1];
      f1.u[0] = r46[0]; f1.u[2] = r46[1];
      f1.u[1] = r57[0]; f1.u[3] = r57[1];
    }

    // ---- PV: O^T += Vt . P ----
    __builtin_amdgcn_s_setprio(1);
#pragma unroll
    for (int dt = 0; dt < 8; ++dt)
      o[dt] = __builtin_amdgcn_mfma_f32_32x32x16_f16(vf0[dt], f0.h, o[dt], 0, 0, 0);
#pragma unroll
    for (int dt = 0; dt < 8; ++dt)
      o[dt] = __builtin_amdgcn_mfma_f32_32x32x16_f16(vf1[dt], f1.h, o[dt], 0, 0, 0);
    __builtin_amdgcn_s_setprio(0);
    cur ^= 1;
  }

  // ---- merge wave1's partial into wave0, then epilogue (wave0 only) ----
  __syncthreads();
  if (wv == 1) {
    float* dst = (float*)(smem + 32768);   // [128][64]
#pragma unroll
    for (int dt = 0; dt < 8; ++dt)
#pragma unroll
      for (int r = 0; r < 16; ++r)
        dst[(dt * 16 + r) * 64 + l] = o[dt][r];
    ((float*)smem)[l]      = m_r;
    ((float*)smem)[64 + l] = l_r;
  }
  __syncthreads();
  if (wv == 0) {
    float m1 = ((float*)smem)[l];
    float l1 = ((float*)smem)[64 + l];
    float M   = fmaxf(m_r, m1);
    float sc0 = __builtin_amdgcn_exp2f(m_r - M);
    float sc1 = __builtin_amdgcn_exp2f(m1 - M);
    float lt  = l_r * sc0 + l1 * sc1;
    float inv = 1.0f / (lt * 8.0f);      // includes post-softmax /sqrt(64)
    const float* src = (const float*)(smem + 32768);
    float* chunk = (float*)(smem + 4096);   // [32 q][33 d] fp32
    float* ob = out + ((size_t)(b * T_ + q0)) * 1024;
#pragma unroll
    for (int dt = 0; dt < 8; ++dt) {
      WAIT_LGKM0();
#pragma unroll
      for (int r = 0; r < 16; ++r) {
        int dl = (r & 3) + 8 * (r >> 2) + 4 * g;
        float merged = (o[dt][r] * sc0 + src[(dt * 16 + r) * 64 + l] * sc1) * inv;
        chunk[ln * 33 + dl] = merged;
      }
      WAIT_LGKM0();
#pragma unroll
      for (int rr = 0; rr < 2; ++rr) {
        int qq = (l >> 2) + 16 * rr;
        int cp = (l & 3) * 8;
        float vv[8];
#pragma unroll
        for (int jj = 0; jj < 8; ++jj) vv[jj] = chunk[qq * 33 + cp + jj];
        float4 w0 = make_float4(vv[0], vv[1], vv[2], vv[3]);
        float4 w1 = make_float4(vv[4], vv[5], vv[6], vv[7]);
        float* orow = ob + (size_t)qq * 1024 + dt * 32 + cp;
#pragma unroll
        for (int rep = 0; rep < 4; ++rep) {
          *(float4*)(orow + rep * 256)     = w0;
          *(float4*)(orow + rep * 256 + 4) = w1;
        }
      }
    }
  }
}

extern "C" void kernel_launch(void* const* d_in, const int* in_sizes, int n_in,
                              void* d_out, int out_size, void* d_ws, size_t ws_size,
                              hipStream_t stream) {
  const float* x  = (const float*)d_in[0];
  const float* Wq = (const float*)d_in[1];
  const float* bq = (const float*)d_in[2];
  const float* Wk = (const float*)d_in[3];
  const float* bk = (const float*)d_in[4];
  const float* Wv = (const float*)d_in[5];
  const float* bv = (const float*)d_in[6];
  float* out = (float*)d_out;
  char* ws = (char*)d_ws;
  _Float16* Wt   = (_Float16*)ws;                         // 1.5 MB
  float*    bcat = (float*)(ws + 0x180000);               // 3 KB (pad to 4 KB)
  _Float16* Qh   = (_Float16*)(ws + 0x181000);            // 8 MB
  _Float16* Kh   = Qh + (size_t)16384 * 256;              // 8 MB
  _Float16* Vt   = Kh + (size_t)16384 * 256;              // 8 MB  (total ~25.6 MB)

  prep_w<<<3072, 256, 0, stream>>>(Wq, bq, Wk, bk, Wv, bv, Wt, bcat);
  qkv_gemm<<<dim3(128, 6), 256, 0, stream>>>(x, Wt, bcat, Qh, Kh, Vt);
  attn_mfma<<<512, 128, 0, stream>>>(Qh, Kh, Vt, out);
}